// Round 1
// baseline (457.013 us; speedup 1.0000x reference)
//
#include <hip/hip_runtime.h>
#include <math.h>

typedef unsigned short u16;
typedef __attribute__((ext_vector_type(8))) short bf8;          // 8 x bf16 (4 VGPR) MFMA frag
typedef __attribute__((ext_vector_type(4))) float f4;           // MFMA acc
typedef __attribute__((ext_vector_type(4))) unsigned int u32x4; // 16B staging
typedef __attribute__((ext_vector_type(4))) unsigned short u16x4;
typedef __attribute__((ext_vector_type(8))) unsigned short u16x8;

__device__ __forceinline__ float bf2f(u16 a){
  unsigned u = ((unsigned)a) << 16;
  float f; __builtin_memcpy(&f, &u, 4);
  return f;
}
__device__ __forceinline__ u16 f2bf(float f){
  unsigned u; __builtin_memcpy(&u, &f, 4);
  u += 0x7fffu + ((u >> 16) & 1u);   // RNE
  return (u16)(u >> 16);
}

// ---------------- transpose + cast: in[R][C] f32 -> out[C][R] bf16 ----------
__global__ void k_transpose_cast(const float* __restrict__ in, u16* __restrict__ out,
                                 int R, int C){
  __shared__ float tile[32][33];
  const int bx = blockIdx.x * 32, by = blockIdx.y * 32;
  const int tx = threadIdx.x, ty = threadIdx.y;   // (32,8)
#pragma unroll
  for (int i = 0; i < 4; i++)
    tile[ty + i*8][tx] = in[(size_t)(by + ty + i*8) * C + bx + tx];
  __syncthreads();
#pragma unroll
  for (int i = 0; i < 4; i++)
    out[(size_t)(bx + ty + i*8) * R + by + tx] = f2bf(tile[tx][ty + i*8]);
}

// ---------------- LayerNorm: f32 in -> optional f32 out + bf16 out ----------
__global__ __launch_bounds__(256) void k_layernorm(
    const float* __restrict__ in, const float* __restrict__ gam,
    const float* __restrict__ bet, float* __restrict__ outf,
    u16* __restrict__ outb, int D)
{
  const int row = blockIdx.x, t = threadIdx.x;
  const int nv = D >> 8;                 // 2 (D=512) or 3 (D=768)
  const float* r = in + (size_t)row * D;
  float v[3] = {0.f, 0.f, 0.f};
  float s = 0.f, s2 = 0.f;
#pragma unroll
  for (int i = 0; i < 3; i++){
    if (i < nv){ float xx = r[t + i*256]; v[i] = xx; s += xx; s2 += xx*xx; }
  }
#pragma unroll
  for (int m = 32; m; m >>= 1){ s += __shfl_xor(s, m); s2 += __shfl_xor(s2, m); }
  __shared__ float rs[4], rq[4];
  const int wave = t >> 6;
  if ((t & 63) == 0){ rs[wave] = s; rq[wave] = s2; }
  __syncthreads();
  s  = rs[0] + rs[1] + rs[2] + rs[3];
  s2 = rq[0] + rq[1] + rq[2] + rq[3];
  const float mean = s / (float)D;
  const float var  = s2 / (float)D - mean * mean;
  const float rstd = rsqrtf(var + 1e-5f);
#pragma unroll
  for (int i = 0; i < 3; i++){
    if (i < nv){
      const int c = t + i*256;
      float o = (v[i] - mean) * rstd * gam[c] + bet[c];
      if (outf) outf[(size_t)row * D + c] = o;
      outb[(size_t)row * D + c] = f2bf(o);
    }
  }
}

// ---------------- bf16 MFMA GEMM: C = A[M,K] @ BT[N,K]^T, fused epilogue ----
// OUTM: 0 = f32 out, 1 = bf16 out, 2 = bf16 transposed out [b*512+n][2048]
template<bool BIAS, bool RES, bool GELU_ACT, int OUTM>
__global__ __launch_bounds__(256) void k_gemm(
    const u16* __restrict__ A, const u16* __restrict__ BT,
    const float* __restrict__ bias, const float* __restrict__ res,
    float* __restrict__ outf, u16* __restrict__ outb,
    int M, int N, int K)
{
  __shared__ u16 As[128 * 64];
  __shared__ u16 Bs[128 * 64];
  const int t = threadIdx.x;
  const int m0 = blockIdx.y * 128, n0 = blockIdx.x * 128;
  const int wave = t >> 6, lane = t & 63;
  const int wm = wave >> 1, wn = wave & 1;
  const int l15 = lane & 15, lg = lane >> 4;
  const int srow = t >> 3;             // staging row 0..31 (+i*32)
  const int scol = (t & 7) << 3;       // staging col in elements (0..56)
  const u16* Ag = A + (size_t)m0 * K;
  const u16* Bg = BT + (size_t)n0 * K;

  f4 acc[4][4];
#pragma unroll
  for (int i = 0; i < 4; i++)
#pragma unroll
    for (int j = 0; j < 4; j++) acc[i][j] = (f4){0.f, 0.f, 0.f, 0.f};

  u32x4 ra[4], rb[4];
#pragma unroll
  for (int i = 0; i < 4; i++){
    const int row = i*32 + srow;
    ra[i] = *(const u32x4*)(Ag + (size_t)row * K + scol);
    rb[i] = *(const u32x4*)(Bg + (size_t)row * K + scol);
  }
  const int nK = K >> 6;
  for (int kt = 0;; kt++){
    __syncthreads();
#pragma unroll
    for (int i = 0; i < 4; i++){
      const int row = i*32 + srow;
      const int sw = (scol * 2) ^ ((row & 7) << 4);     // XOR swizzle (bytes)
      *(u32x4*)((char*)As + row*128 + sw) = ra[i];
      *(u32x4*)((char*)Bs + row*128 + sw) = rb[i];
    }
    if (kt + 1 < nK){
      const int ko = (kt + 1) << 6;
#pragma unroll
      for (int i = 0; i < 4; i++){
        const int row = i*32 + srow;
        ra[i] = *(const u32x4*)(Ag + (size_t)row * K + ko + scol);
        rb[i] = *(const u32x4*)(Bg + (size_t)row * K + ko + scol);
      }
    }
    __syncthreads();
#pragma unroll
    for (int kc = 0; kc < 2; kc++){
      bf8 af[4], bfr[4];
      const int kb = kc*64 + lg*16;                     // byte offset in row
#pragma unroll
      for (int mf = 0; mf < 4; mf++){
        const int row = wm*64 + mf*16 + l15;
        af[mf] = *(const bf8*)((char*)As + row*128 + (kb ^ ((row & 7) << 4)));
      }
#pragma unroll
      for (int nf = 0; nf < 4; nf++){
        const int row = wn*64 + nf*16 + l15;
        bfr[nf] = *(const bf8*)((char*)Bs + row*128 + (kb ^ ((row & 7) << 4)));
      }
#pragma unroll
      for (int mf = 0; mf < 4; mf++)
#pragma unroll
        for (int nf = 0; nf < 4; nf++)
          acc[mf][nf] = __builtin_amdgcn_mfma_f32_16x16x32_bf16(af[mf], bfr[nf], acc[mf][nf], 0, 0, 0);
    }
    if (kt + 1 == nK) break;
  }
  // epilogue
#pragma unroll
  for (int mf = 0; mf < 4; mf++){
#pragma unroll
    for (int nf = 0; nf < 4; nf++){
      const int colg = n0 + wn*64 + nf*16 + l15;
      const int rowg = m0 + wm*64 + mf*16 + lg*4;
      const float bv = BIAS ? bias[colg] : 0.f;
      float vv[4];
#pragma unroll
      for (int j = 0; j < 4; j++){
        float v = acc[mf][nf][j] + bv;
        if (RES) v += res[(size_t)(rowg + j) * N + colg];
        if (GELU_ACT) v = 0.5f * v * (1.f + erff(v * 0.7071067811865475f));
        vv[j] = v;
      }
      if (OUTM == 0){
#pragma unroll
        for (int j = 0; j < 4; j++) outf[(size_t)(rowg + j) * N + colg] = vv[j];
      } else if (OUTM == 1){
#pragma unroll
        for (int j = 0; j < 4; j++) outb[(size_t)(rowg + j) * N + colg] = f2bf(vv[j]);
      } else {
        const int bb = rowg >> 11, ss = rowg & 2047;    // per-batch transpose
        u16x4 pk;
#pragma unroll
        for (int j = 0; j < 4; j++) pk[j] = f2bf(vv[j]);
        *(u16x4*)(outb + ((size_t)(bb*512 + colg)) * 2048 + ss) = pk;
      }
    }
  }
}

// ---------------- flash cross-attention: q,k [B,S,512] bf16, vt [B*512,2048] -
__global__ __launch_bounds__(256) void k_flash(
    const u16* __restrict__ q, const u16* __restrict__ k,
    const u16* __restrict__ vt, u16* __restrict__ ctx)
{
  __shared__ u16 plds[4][16 * 72];
  const int wave = threadIdx.x >> 6, lane = threadIdx.x & 63;
  const int l15 = lane & 15, lg = lane >> 4;
  const int qb = blockIdx.x, bh = blockIdx.y;
  const int b = bh >> 3, h = bh & 7;
  const int qrow0 = qb*64 + wave*16;

  const u16* qp = q + ((size_t)(b*2048 + qrow0 + l15)) * 512 + h*64 + lg*8;
  const bf8 qf0 = *(const bf8*)qp;
  const bf8 qf1 = *(const bf8*)(qp + 32);

  f4 o[4];
  float rm[4], rl[4];
#pragma unroll
  for (int i = 0; i < 4; i++){ o[i] = (f4){0.f,0.f,0.f,0.f}; rm[i] = -1e30f; rl[i] = 0.f; }
  u16* myp = plds[wave];
  const u16* kbase = k + (size_t)(b*2048) * 512 + h*64 + lg*8;
  const u16* vbase = vt + ((size_t)(b*512 + h*64 + l15)) * 2048 + lg*8;

  for (int kt = 0; kt < 2048; kt += 64){
    f4 s[4];
#pragma unroll
    for (int nb = 0; nb < 4; nb++){
      const u16* kp = kbase + (size_t)(kt + nb*16 + l15) * 512;
      const bf8 kf0 = *(const bf8*)kp;
      const bf8 kf1 = *(const bf8*)(kp + 32);
      f4 a = (f4){0.f,0.f,0.f,0.f};
      a = __builtin_amdgcn_mfma_f32_16x16x32_bf16(qf0, kf0, a, 0, 0, 0);
      a = __builtin_amdgcn_mfma_f32_16x16x32_bf16(qf1, kf1, a, 0, 0, 0);
#pragma unroll
      for (int j = 0; j < 4; j++) s[nb][j] = a[j] * 0.125f;
    }
    float pm[4], al[4], rsum[4];
#pragma unroll
    for (int j = 0; j < 4; j++)
      pm[j] = fmaxf(fmaxf(s[0][j], s[1][j]), fmaxf(s[2][j], s[3][j]));
#pragma unroll
    for (int j = 0; j < 4; j++){
      pm[j] = fmaxf(pm[j], __shfl_xor(pm[j], 1));
      pm[j] = fmaxf(pm[j], __shfl_xor(pm[j], 2));
      pm[j] = fmaxf(pm[j], __shfl_xor(pm[j], 4));
      pm[j] = fmaxf(pm[j], __shfl_xor(pm[j], 8));
    }
#pragma unroll
    for (int j = 0; j < 4; j++){
      const float mn = fmaxf(rm[j], pm[j]);
      al[j] = __expf(rm[j] - mn);
      rm[j] = mn;
    }
#pragma unroll
    for (int nb = 0; nb < 4; nb++)
#pragma unroll
      for (int j = 0; j < 4; j++) s[nb][j] = __expf(s[nb][j] - rm[j]);
#pragma unroll
    for (int j = 0; j < 4; j++){
      rsum[j] = s[0][j] + s[1][j] + s[2][j] + s[3][j];
      rsum[j] += __shfl_xor(rsum[j], 1);
      rsum[j] += __shfl_xor(rsum[j], 2);
      rsum[j] += __shfl_xor(rsum[j], 4);
      rsum[j] += __shfl_xor(rsum[j], 8);
      rl[j] = rl[j] * al[j] + rsum[j];
    }
#pragma unroll
    for (int nb = 0; nb < 4; nb++)
#pragma unroll
      for (int j = 0; j < 4; j++) o[nb][j] *= al[j];
    // P (C-layout) -> LDS -> A-fragment layout
#pragma unroll
    for (int nb = 0; nb < 4; nb++)
#pragma unroll
      for (int j = 0; j < 4; j++)
        myp[(lg*4 + j) * 72 + nb*16 + l15] = f2bf(s[nb][j]);
    asm volatile("s_waitcnt lgkmcnt(0)" ::: "memory");
    const bf8 pf0 = *(const bf8*)(myp + l15*72 + lg*8);
    const bf8 pf1 = *(const bf8*)(myp + l15*72 + 32 + lg*8);
#pragma unroll
    for (int nb = 0; nb < 4; nb++){
      const u16* vp = vbase + (size_t)(nb*16) * 2048 + kt;
      const bf8 vf0 = *(const bf8*)vp;
      const bf8 vf1 = *(const bf8*)(vp + 32);
      o[nb] = __builtin_amdgcn_mfma_f32_16x16x32_bf16(pf0, vf0, o[nb], 0, 0, 0);
      o[nb] = __builtin_amdgcn_mfma_f32_16x16x32_bf16(pf1, vf1, o[nb], 0, 0, 0);
    }
  }
#pragma unroll
  for (int j = 0; j < 4; j++) rl[j] = 1.f / rl[j];
#pragma unroll
  for (int nb = 0; nb < 4; nb++)
#pragma unroll
    for (int j = 0; j < 4; j++)
      ctx[((size_t)(b*2048 + qrow0 + lg*4 + j)) * 512 + h*64 + nb*16 + l15] =
          f2bf(o[nb][j] * rl[j]);
}

// ---------------- tiny MHA (batch_first=False: attends over L=4) ------------
__global__ __launch_bounds__(256) void k_mha_small(const u16* __restrict__ qkv,
                                                   u16* __restrict__ outb)
{
  const int tid = blockIdx.x * 256 + threadIdx.x;  // 65536 threads
  const int n = tid & 2047;
  const int hl = tid >> 11;
  const int h = hl >> 2, l = hl & 3;
  const u16* qp = qkv + ((size_t)l * 2048 + n) * 1536 + h*64;
  float qv[64];
#pragma unroll
  for (int i = 0; i < 8; i++){
    const bf8 c = *(const bf8*)(qp + i*8);
#pragma unroll
    for (int j2 = 0; j2 < 8; j2++) qv[i*8 + j2] = bf2f((u16)c[j2]) * 0.125f;
  }
  float sc[4];
#pragma unroll
  for (int m = 0; m < 4; m++){
    const u16* kp = qkv + ((size_t)m * 2048 + n) * 1536 + 512 + h*64;
    float a = 0.f;
#pragma unroll
    for (int i = 0; i < 8; i++){
      const bf8 c = *(const bf8*)(kp + i*8);
#pragma unroll
      for (int j2 = 0; j2 < 8; j2++) a += qv[i*8 + j2] * bf2f((u16)c[j2]);
    }
    sc[m] = a;
  }
  const float mx = fmaxf(fmaxf(sc[0], sc[1]), fmaxf(sc[2], sc[3]));
  float p[4]; float sum = 0.f;
#pragma unroll
  for (int m = 0; m < 4; m++){ p[m] = __expf(sc[m] - mx); sum += p[m]; }
  const float inv = 1.f / sum;
  float ov[64];
#pragma unroll
  for (int i = 0; i < 64; i++) ov[i] = 0.f;
#pragma unroll
  for (int m = 0; m < 4; m++){
    const float pw = p[m] * inv;
    const u16* vp = qkv + ((size_t)m * 2048 + n) * 1536 + 1024 + h*64;
#pragma unroll
    for (int i = 0; i < 8; i++){
      const bf8 c = *(const bf8*)(vp + i*8);
#pragma unroll
      for (int j2 = 0; j2 < 8; j2++) ov[i*8 + j2] += pw * bf2f((u16)c[j2]);
    }
  }
  u16* op = outb + ((size_t)l * 2048 + n) * 512 + h*64;
#pragma unroll
  for (int i = 0; i < 8; i++){
    u16x8 pk;
#pragma unroll
    for (int j2 = 0; j2 < 8; j2++) pk[j2] = f2bf(ov[i*8 + j2]);
    *(u16x8*)(op + i*8) = pk;
  }
}

// ---------------------------------------------------------------------------
extern "C" void kernel_launch(void* const* d_in, const int* in_sizes, int n_in,
                              void* d_out, int out_size, void* d_ws, size_t ws_size,
                              hipStream_t stream)
{
  (void)in_sizes; (void)n_in; (void)out_size; (void)ws_size;
  const float* x    = (const float*)d_in[0];
  const float* y    = (const float*)d_in[1];
  const float* Wq   = (const float*)d_in[2];
  const float* Wk   = (const float*)d_in[3];
  const float* Wv   = (const float*)d_in[4];
  const float* Wo   = (const float*)d_in[5];
  const float* bo   = (const float*)d_in[6];
  const float* Win  = (const float*)d_in[7];
  const float* bin  = (const float*)d_in[8];
  const float* Wmo  = (const float*)d_in[9];
  const float* bmo  = (const float*)d_in[10];
  const float* ln1g = (const float*)d_in[11];
  const float* ln1b = (const float*)d_in[12];
  const float* ln2g = (const float*)d_in[13];
  const float* ln2b = (const float*)d_in[14];
  const float* ln3g = (const float*)d_in[15];
  const float* ln3b = (const float*)d_in[16];
  const float* ln4g = (const float*)d_in[17];
  const float* ln4b = (const float*)d_in[18];
  const float* W1   = (const float*)d_in[19];
  const float* b1   = (const float*)d_in[20];
  const float* W2   = (const float*)d_in[21];
  const float* b2   = (const float*)d_in[22];

  char* ws = (char*)d_ws;
  const size_t MB = 1024 * 1024;
  // bf16 transposed weights (~8.5 MB)
  u16* WqT  = (u16*)ws;
  u16* WkT  = WqT  + 512 * 512;
  u16* WvT  = WkT  + 512 * 768;
  u16* WoT  = WvT  + 512 * 768;
  u16* WinT = WoT  + 512 * 512;
  u16* WmoT = WinT + 1536 * 512;
  u16* W1T  = WmoT + 512 * 512;
  u16* W2T  = W1T  + 2048 * 512;
  // activation regions with lifetime-based reuse (total ws use = 109 MB)
  float* hF   = (float*)(ws + 9 * MB);    // 16MB: h_f32      ; later t1 low half
  float* xnF  = (float*)(ws + 25 * MB);   // 16MB: xn_f32 -> sar_f32 ; later t1 high half
  float* carF = (float*)(ws + 41 * MB);   // 16MB: car_f32 -> h2_f32
  u16* xnB  = (u16*)(ws + 57 * MB);       //  8MB: xn_bf  -> sa_in_bf
  u16* ynB  = (u16*)(ws + 65 * MB);       // 12MB: yn_bf  -> h_bf
  u16* qB   = (u16*)(ws + 77 * MB);       //  8MB: q_bf   -> h2_bf
  u16* kB   = (u16*)(ws + 85 * MB);       //  8MB: k_bf   ┐
  u16* vtB  = (u16*)(ws + 93 * MB);       //  8MB: vt_bf  ├ qkv_bf (24MB)
  u16* ctxB = (u16*)(ws + 101 * MB);      //  8MB: ctx_bf ┘
  float* sarF = xnF;
  float* h2F  = carF;
  u16* saB   = xnB;
  u16* hB    = ynB;
  u16* h2B   = qB;
  u16* qkvB  = kB;
  u16* t1B   = (u16*)hF;

  const dim3 tb(32, 8);
  k_transpose_cast<<<dim3(16, 16), tb, 0, stream>>>(Wq,  WqT,  512,  512);
  k_transpose_cast<<<dim3(16, 24), tb, 0, stream>>>(Wk,  WkT,  768,  512);
  k_transpose_cast<<<dim3(16, 24), tb, 0, stream>>>(Wv,  WvT,  768,  512);
  k_transpose_cast<<<dim3(16, 16), tb, 0, stream>>>(Wo,  WoT,  512,  512);
  k_transpose_cast<<<dim3(48, 16), tb, 0, stream>>>(Win, WinT, 512, 1536);
  k_transpose_cast<<<dim3(16, 16), tb, 0, stream>>>(Wmo, WmoT, 512,  512);
  k_transpose_cast<<<dim3(64, 16), tb, 0, stream>>>(W1,  W1T,  512, 2048);
  k_transpose_cast<<<dim3(16, 64), tb, 0, stream>>>(W2,  W2T, 2048,  512);

  k_layernorm<<<8192, 256, 0, stream>>>(x, ln1g, ln1b, xnF, xnB, 512);
  k_layernorm<<<8192, 256, 0, stream>>>(y, ln2g, ln2b, (float*)nullptr, ynB, 768);

  // q/k/v projections (v stored transposed per batch for the PV step)
  k_gemm<false,false,false,1><<<dim3(4, 64), 256, 0, stream>>>(xnB, WqT, nullptr, nullptr, nullptr, qB,  8192, 512, 512);
  k_gemm<false,false,false,1><<<dim3(4, 64), 256, 0, stream>>>(ynB, WkT, nullptr, nullptr, nullptr, kB,  8192, 512, 768);
  k_gemm<false,false,false,2><<<dim3(4, 64), 256, 0, stream>>>(ynB, WvT, nullptr, nullptr, nullptr, vtB, 8192, 512, 768);

  k_flash<<<dim3(32, 32), 256, 0, stream>>>(qB, kB, vtB, ctxB);

  // ca = ctx@Wo + bo + xn  -> LN3 -> h
  k_gemm<true,true,false,0><<<dim3(4, 64), 256, 0, stream>>>(ctxB, WoT, bo, xnF, carF, nullptr, 8192, 512, 512);
  k_layernorm<<<8192, 256, 0, stream>>>(carF, ln3g, ln3b, hF, hB, 512);

  // MHA over L=4: in-proj, tiny attention, out-proj (+h residual) -> LN4 -> h2
  k_gemm<true,false,false,1><<<dim3(12, 64), 256, 0, stream>>>(hB, WinT, bin, nullptr, nullptr, qkvB, 8192, 1536, 512);
  k_mha_small<<<256, 256, 0, stream>>>(qkvB, saB);
  k_gemm<true,true,false,0><<<dim3(4, 64), 256, 0, stream>>>(saB, WmoT, bmo, hF, sarF, nullptr, 8192, 512, 512);
  k_layernorm<<<8192, 256, 0, stream>>>(sarF, ln4g, ln4b, h2F, h2B, 512);

  // MLP: GELU(h2@W1 + b1)@W2 + b2 + h2 -> d_out (f32)
  k_gemm<true,false,true,1><<<dim3(16, 64), 256, 0, stream>>>(h2B, W1T, b1, nullptr, nullptr, t1B, 8192, 2048, 512);
  k_gemm<true,true,false,0><<<dim3(4, 64), 256, 0, stream>>>(t1B, W2T, b2, h2F, (float*)d_out, nullptr, 8192, 512, 2048);
}